// Round 8
// baseline (62.192 us; speedup 1.0000x reference)
//
#include <hip/hip_runtime.h>

// OrdinalCrossEntropyLoss: out = sum_n sum_{i < t_n} relu(logits[n,i] - logits[n,t_n])
// N = 262144 rows, C = 512 classes, fp32 logits, int targets, scalar fp32 out.
//
// Proven structure (R6): double-buffered 4-row groups, named float4 regs,
// sched_barrier pins next group's 8 loads ahead of current group's consume.
// R8: t is wave-uniform -> readlane to SGPR (scalar branches, sgpr operands).
// Skip the chunk-1 load when t < 256 (it was a fully-clamped duplicate);
// tl then comes from chunk-0 (lane 63's chunk-0 reg always contains elem t
// by the clamp argument). Skip rows with t == 0. -25% issued loads,
// -30% consume VALU; HBM bytes unchanged (clamped loads were L1/L2 hits).

constexpr int C = 512;
constexpr int ROWS_PER_WAVE = 32;          // 8 groups of 4 rows

__device__ __forceinline__ float rl63(float x) {
    return __int_as_float(__builtin_amdgcn_readlane(__float_as_int(x), 63));
}

__device__ __forceinline__ void acc4m(float& acc, const float4 v, int i, int t, float tl) {
    acc += (i + 0 < t) ? fmaxf(v.x - tl, 0.0f) : 0.0f;
    acc += (i + 1 < t) ? fmaxf(v.y - tl, 0.0f) : 0.0f;
    acc += (i + 2 < t) ? fmaxf(v.z - tl, 0.0f) : 0.0f;
    acc += (i + 3 < t) ? fmaxf(v.w - tl, 0.0f) : 0.0f;
}

__device__ __forceinline__ void acc4f(float& acc, const float4 v, float tl) {
    acc += fmaxf(v.x - tl, 0.0f) + fmaxf(v.y - tl, 0.0f)
         + fmaxf(v.z - tl, 0.0f) + fmaxf(v.w - tl, 0.0f);
}

__global__ __launch_bounds__(256) void ordinal_ce_kernel(
    const float* __restrict__ logits,
    const int* __restrict__ targets,
    float* __restrict__ out,
    int N)
{
    const int lane    = threadIdx.x & 63;
    const int wave_id = (blockIdx.x * blockDim.x + threadIdx.x) >> 6;
    const int rowbase = wave_id * ROWS_PER_WAVE;

    float acc = 0.0f;

    if (rowbase < N) {
        // Lanes 0..31 own one row's target (coalesced 128B). readlane later.
        int t_l = 0;
        if (lane < ROWS_PER_WAVE && rowbase + lane < N)
            t_l = targets[rowbase + lane];

        const int i0 = lane * 4;          // chunk-0 element index
        const int i1 = i0 + 256;          // chunk-1 element index
        const float4 z4 = make_float4(0.f, 0.f, 0.f, 0.f);

        if (N - rowbase >= ROWS_PER_WAVE) {
            // Two named buffers, 8 float4 each (4 rows x 2 chunks). No arrays.
            float4 A00, A01, A10, A11, A20, A21, A30, A31;
            float4 B00, B01, B10, B11, B20, B21, B30, B31;

// Unconditional load, per-lane offset clamped to the float4 containing t.
#define LDR(p, i, t, co) (*reinterpret_cast<const float4*>((p) + (((i) < (t)) ? (i) : (co))))

// Per row: chunk-0 load always (t==0 rows cost one broadcast line, rare);
// chunk-1 load only when t >= 256 (scalar branch, t is SGPR).
#define LROW(Q0, Q1, p, R) do {                                               \
        const int _t = __builtin_amdgcn_readlane(t_l, (R));                   \
        const int _c = _t & ~3;                                               \
        Q0 = LDR((p), i0, _t, _c);                                            \
        if (_t >= 256) Q1 = LDR((p), i1, _t, _c); else Q1 = z4;               \
    } while (0)

#define LOADG(Q, P) do {                                                      \
        const float* __restrict__ _p =                                        \
            logits + (size_t)(rowbase + 4 * (P)) * C;                         \
        LROW(Q##00, Q##01, _p,         4 * (P) + 0);                          \
        LROW(Q##10, Q##11, _p + C,     4 * (P) + 1);                          \
        LROW(Q##20, Q##21, _p + 2 * C, 4 * (P) + 2);                          \
        LROW(Q##30, Q##31, _p + 3 * C, 4 * (P) + 3);                          \
    } while (0)

// Consume one row. tl extracted in-register: lane 63's chunk-0 reg contains
// elem t when t < 256; lane 63's chunk-1 reg contains it when t >= 256.
#define CROW(Q0, Q1, R) do {                                                  \
        const int _t = __builtin_amdgcn_readlane(t_l, (R));                   \
        if (_t >= 256) {                                                      \
            const float _a  = (_t & 1) ? (Q1).y : (Q1).x;                     \
            const float _b  = (_t & 1) ? (Q1).w : (Q1).z;                     \
            const float _tl = rl63((_t & 2) ? _b : _a);                       \
            acc4f(acc, (Q0), _tl);                                            \
            acc4m(acc, (Q1), i1, _t, _tl);                                    \
        } else if (_t > 0) {                                                  \
            const float _a  = (_t & 1) ? (Q0).y : (Q0).x;                     \
            const float _b  = (_t & 1) ? (Q0).w : (Q0).z;                     \
            const float _tl = rl63((_t & 2) ? _b : _a);                       \
            acc4m(acc, (Q0), i0, _t, _tl);                                    \
        }                                                                     \
    } while (0)

#define CONSG(Q, P) do {                                                      \
        CROW(Q##00, Q##01, 4 * (P) + 0);                                      \
        CROW(Q##10, Q##11, 4 * (P) + 1);                                      \
        CROW(Q##20, Q##21, 4 * (P) + 2);                                      \
        CROW(Q##30, Q##31, 4 * (P) + 3);                                      \
    } while (0)

// Pin: next group's loads must be ISSUED before current group is consumed.
#define SB __builtin_amdgcn_sched_barrier(0)

            LOADG(A, 0);
            LOADG(B, 1); SB; CONSG(A, 0);
            LOADG(A, 2); SB; CONSG(B, 1);
            LOADG(B, 3); SB; CONSG(A, 2);
            LOADG(A, 4); SB; CONSG(B, 3);
            LOADG(B, 5); SB; CONSG(A, 4);
            LOADG(A, 6); SB; CONSG(B, 5);
            LOADG(B, 7); SB; CONSG(A, 6);
            SB;              CONSG(B, 7);
#undef LOADG
#undef LROW
#undef CONSG
#undef CROW
#undef LDR
#undef SB
        } else {
            // Generic tail path (not hit at N=262144).
            const int rows = N - rowbase;
            for (int r = 0; r < rows; ++r) {
                const int t = __builtin_amdgcn_readlane(t_l, r);
                if (t <= 0) continue;
                const float* __restrict__ rp = logits + (size_t)(rowbase + r) * C;
                const float tl = rp[t];                    // broadcast load
                float4 c0 = z4, c1 = z4;
                if (i0 < t) c0 = *reinterpret_cast<const float4*>(rp + i0);
                if (i1 < t) c1 = *reinterpret_cast<const float4*>(rp + i1);
                acc4m(acc, c0, i0, t, tl);
                acc4m(acc, c1, i1, t, tl);
            }
        }
    }

    // Wave reduction (64 lanes)
    #pragma unroll
    for (int off = 32; off > 0; off >>= 1)
        acc += __shfl_down(acc, off, 64);

    // Block reduction: 4 waves
    __shared__ float wave_sums[4];
    const int wib = threadIdx.x >> 6;
    if (lane == 0) wave_sums[wib] = acc;
    __syncthreads();
    if (threadIdx.x == 0) {
        const float s = wave_sums[0] + wave_sums[1] + wave_sums[2] + wave_sums[3];
        atomicAdd(out, s);
    }
}

extern "C" void kernel_launch(void* const* d_in, const int* in_sizes, int n_in,
                              void* d_out, int out_size, void* d_ws, size_t ws_size,
                              hipStream_t stream) {
    const float* logits  = (const float*)d_in[0];
    const int*   targets = (const int*)d_in[1];
    float*       out     = (float*)d_out;

    const int N = in_sizes[1];                 // 262144 rows

    // d_out is poisoned and not re-poisoned between replays; we accumulate.
    hipMemsetAsync(out, 0, sizeof(float) * out_size, stream);

    const int block = 256;
    const int rows_per_block = (block / 64) * ROWS_PER_WAVE;    // 128
    const int grid = (N + rows_per_block - 1) / rows_per_block; // 2048
    ordinal_ce_kernel<<<grid, block, 0, stream>>>(logits, targets, out, N);
}

// Round 9
// 56.888 us; speedup vs baseline: 1.0932x; 1.0932x over previous
//
#include <hip/hip_runtime.h>

// OrdinalCrossEntropyLoss: out = sum_n sum_{i < t_n} relu(logits[n,i] - logits[n,t_n])
// N = 262144 rows, C = 512 classes, fp32 logits, int targets, scalar fp32 out.
//
// R6 structure (best, 57.0us): double-buffered 4-row groups, named float4
// regs, clamped cndmask loads (branch-free load phase), sched_barrier pins
// next group's loads ahead of current group's consume.
// R8 lesson: scalar branches in the load phase fragment the pinned schedule
// (62us). R9: single change vs R6 — prefetch distance 2 (triple buffer
// A/B/C), so a group is consumed ~2 phases after issue (~600+cyc of cover
// vs ~300). Tests whether the 57->~48us gap is exposed latency or DRAM
// pattern. VGPR ~116 -> 4 waves/SIMD (down from 5) is the tradeoff.

constexpr int C = 512;
constexpr int ROWS_PER_WAVE = 32;          // 8 groups of 4 rows

__device__ __forceinline__ void acc4(float& acc, const float4 v, int i, int t, float tl) {
    acc += (i + 0 < t) ? fmaxf(v.x - tl, 0.0f) : 0.0f;
    acc += (i + 1 < t) ? fmaxf(v.y - tl, 0.0f) : 0.0f;
    acc += (i + 2 < t) ? fmaxf(v.z - tl, 0.0f) : 0.0f;
    acc += (i + 3 < t) ? fmaxf(v.w - tl, 0.0f) : 0.0f;
}

__global__ __launch_bounds__(256) void ordinal_ce_kernel(
    const float* __restrict__ logits,
    const int* __restrict__ targets,
    float* __restrict__ out,
    int N)
{
    const int lane    = threadIdx.x & 63;
    const int wave_id = (blockIdx.x * blockDim.x + threadIdx.x) >> 6;
    const int rowbase = wave_id * ROWS_PER_WAVE;

    float acc = 0.0f;

    if (rowbase < N) {
        // Metadata preload: lanes 0..31 own one row each (coalesced targets,
        // 32 parallel tl gathers). Later reads come from registers via shfl.
        int   t_l  = 0;
        float tl_l = 0.0f;
        if (lane < ROWS_PER_WAVE && rowbase + lane < N) {
            const int r = rowbase + lane;
            t_l  = targets[r];
            tl_l = logits[(size_t)r * C + t_l];
        }

        const int i0 = lane * 4;          // chunk-0 element index
        const int i1 = i0 + 256;          // chunk-1 element index

        if (N - rowbase >= ROWS_PER_WAVE) {
            // Three named buffers, 8 float4 each (4 rows x 2 chunks). No arrays.
            float4 A00, A01, A10, A11, A20, A21, A30, A31;
            float4 B00, B01, B10, B11, B20, B21, B30, B31;
            float4 C00, C01, C10, C11, C20, C21, C30, C31;

// Unconditional loads with clamped per-lane offset: lanes past the prefix
// re-read the row-base line (L1/L2 broadcast hit, no HBM cost, no exec mask).
#define LDR(p, i, t) (*reinterpret_cast<const float4*>((p) + (((i) < (t)) ? (i) : 0)))

#define LOADG(Q, P) do {                                                       \
        const int _t0 = __shfl(t_l, 4 * (P) + 0, 64);                          \
        const int _t1 = __shfl(t_l, 4 * (P) + 1, 64);                          \
        const int _t2 = __shfl(t_l, 4 * (P) + 2, 64);                          \
        const int _t3 = __shfl(t_l, 4 * (P) + 3, 64);                          \
        const float* __restrict__ _p =                                         \
            logits + (size_t)(rowbase + 4 * (P)) * C;                          \
        Q##00 = LDR(_p,         i0, _t0);  Q##01 = LDR(_p,         i1, _t0);   \
        Q##10 = LDR(_p + C,     i0, _t1);  Q##11 = LDR(_p + C,     i1, _t1);   \
        Q##20 = LDR(_p + 2 * C, i0, _t2);  Q##21 = LDR(_p + 2 * C, i1, _t2);   \
        Q##30 = LDR(_p + 3 * C, i0, _t3);  Q##31 = LDR(_p + 3 * C, i1, _t3);   \
    } while (0)

#define CONSG(Q, P) do {                                                       \
        const int   _t0  = __shfl(t_l,  4 * (P) + 0, 64);                      \
        const float _tl0 = __shfl(tl_l, 4 * (P) + 0, 64);                      \
        const int   _t1  = __shfl(t_l,  4 * (P) + 1, 64);                      \
        const float _tl1 = __shfl(tl_l, 4 * (P) + 1, 64);                      \
        const int   _t2  = __shfl(t_l,  4 * (P) + 2, 64);                      \
        const float _tl2 = __shfl(tl_l, 4 * (P) + 2, 64);                      \
        const int   _t3  = __shfl(t_l,  4 * (P) + 3, 64);                      \
        const float _tl3 = __shfl(tl_l, 4 * (P) + 3, 64);                      \
        acc4(acc, Q##00, i0, _t0, _tl0); acc4(acc, Q##01, i1, _t0, _tl0);      \
        acc4(acc, Q##10, i0, _t1, _tl1); acc4(acc, Q##11, i1, _t1, _tl1);      \
        acc4(acc, Q##20, i0, _t2, _tl2); acc4(acc, Q##21, i1, _t2, _tl2);      \
        acc4(acc, Q##30, i0, _t3, _tl3); acc4(acc, Q##31, i1, _t3, _tl3);      \
    } while (0)

// Pin: loads of group P+2 must be ISSUED before group P is consumed.
#define SB __builtin_amdgcn_sched_barrier(0)

            LOADG(A, 0); LOADG(B, 1);
            LOADG(C, 2); SB; CONSG(A, 0);
            LOADG(A, 3); SB; CONSG(B, 1);
            LOADG(B, 4); SB; CONSG(C, 2);
            LOADG(C, 5); SB; CONSG(A, 3);
            LOADG(A, 6); SB; CONSG(B, 4);
            LOADG(B, 7); SB; CONSG(C, 5);
            SB;              CONSG(A, 6);
            CONSG(B, 7);
#undef LOADG
#undef CONSG
#undef LDR
#undef SB
        } else {
            // Generic tail path (not hit at N=262144).
            const int rows = N - rowbase;
            const float4 z4 = make_float4(0.f, 0.f, 0.f, 0.f);
            for (int r = 0; r < rows; ++r) {
                const int   t  = __shfl(t_l,  r, 64);
                const float tl = __shfl(tl_l, r, 64);
                if (t <= 0) continue;
                const float* __restrict__ rp = logits + (size_t)(rowbase + r) * C;
                float4 c0 = z4, c1 = z4;
                if (i0 < t) c0 = *reinterpret_cast<const float4*>(rp + i0);
                if (i1 < t) c1 = *reinterpret_cast<const float4*>(rp + i1);
                acc4(acc, c0, i0, t, tl);
                acc4(acc, c1, i1, t, tl);
            }
        }
    }

    // Wave reduction (64 lanes)
    #pragma unroll
    for (int off = 32; off > 0; off >>= 1)
        acc += __shfl_down(acc, off, 64);

    // Block reduction: 4 waves
    __shared__ float wave_sums[4];
    const int wib = threadIdx.x >> 6;
    if (lane == 0) wave_sums[wib] = acc;
    __syncthreads();
    if (threadIdx.x == 0) {
        const float s = wave_sums[0] + wave_sums[1] + wave_sums[2] + wave_sums[3];
        atomicAdd(out, s);
    }
}

extern "C" void kernel_launch(void* const* d_in, const int* in_sizes, int n_in,
                              void* d_out, int out_size, void* d_ws, size_t ws_size,
                              hipStream_t stream) {
    const float* logits  = (const float*)d_in[0];
    const int*   targets = (const int*)d_in[1];
    float*       out     = (float*)d_out;

    const int N = in_sizes[1];                 // 262144 rows

    // d_out is poisoned and not re-poisoned between replays; we accumulate.
    hipMemsetAsync(out, 0, sizeof(float) * out_size, stream);

    const int block = 256;
    const int rows_per_block = (block / 64) * ROWS_PER_WAVE;    // 128
    const int grid = (N + rows_per_block - 1) / rows_per_block; // 2048
    ordinal_ce_kernel<<<grid, block, 0, stream>>>(logits, targets, out, N);
}